// Round 6
// baseline (8499.435 us; speedup 1.0000x reference)
//
#include <hip/hip_runtime.h>
#include <math.h>

// ---------------------------------------------------------------------------
// DisableGateLSTM: 512-step LSTM over 64 independent chains.
// R6 restructure: 2 groups x 128 blocks (1/CU). Group g owns 32 chains,
// processed as TWO interleaved sub-batches A/B of 16 chains. While A's
// h(t+1) propagates through the LLC (publish->flag->detect->load), the
// block computes B's full sub-step (~2us of real work) -- hiding the
// cross-CU latency that R4/R5 left exposed (~7us/step stall at identical
// VALU%). Block j owns 4 hidden units (16 gate rows); weights LDS-resident.
// All cross-block traffic uses relaxed agent-scope atomics (no acquire/
// release cache maintenance -- R1 lesson). Exact libm expf/tanhf (R2
// lesson). No non-injective swizzles (R3 lesson): all LDS layouts are
// linear strides + per-row 16B skews, 2-way bank aliasing max (free).
// ---------------------------------------------------------------------------

#define BATCH   64
#define SEQ     512
#define EMBED   256
#define HIDDEN  512
#define GD      768
#define CLASSES 4

#define NBLK    256
#define NTHR    512
#define GROUPS  2
#define GB      128          // blocks per group
#define SUBS    2            // sub-batches per group
#define CPG     16           // chains per sub-batch
#define UPB     4            // hidden units per block
#define ROWS    16           // 4 gates * UPB

// LDS strides (floats); skew = (row>>2)*4 resp (chain>>2)*4 gives <=2-way
// bank aliasing on every hot GEMM access pattern (verified arithmetic).
#define SWHS 532
#define SWXS 276
#define SHS  544             // 16*544 = 8704 floats; reduce scratch needs 512*17=8704: exact fit
#define SXS  268

__global__ __launch_bounds__(NTHR, 1) void lstm_persistent(
    const int*   __restrict__ ids,
    const float* __restrict__ emb,
    const float* __restrict__ Wf, const float* __restrict__ bf,
    const float* __restrict__ Wi, const float* __restrict__ bi,
    const float* __restrict__ Wo, const float* __restrict__ bo,
    const float* __restrict__ Wc, const float* __restrict__ bc,
    const float* __restrict__ fcw,
    const float* __restrict__ fcb,
    float* __restrict__ out,
    float* __restrict__ ws)
{
  __shared__ __align__(16) float sWh[ROWS * SWHS];   // 34,048 B
  __shared__ __align__(16) float sWx[ROWS * SWXS];   // 17,664 B
  __shared__ __align__(16) float sH [CPG * SHS];     // 34,816 B (= reduce scratch)
  __shared__ __align__(16) float sX [CPG * SXS];     // 17,152 B
  __shared__ float sG[ROWS][CPG];
  __shared__ float sC[SUBS][UPB][CPG];
  __shared__ float sM[SUBS][UPB][CPG];
  __shared__ float sB[ROWS];

  const int tid = threadIdx.x;
  const int bid = blockIdx.x;
  const int g   = bid & 1;        // group 0..1
  const int j   = bid >> 1;       // in-group rank 0..127
  const int u0  = j * UPB;

  float*    hbuf  = ws;                                   // [2][64][512]
  float*    wmax  = ws + (size_t)2 * BATCH * HIDDEN;      // [64][512]
  unsigned* flagsBase = (unsigned*)(ws + (size_t)3 * BATCH * HIDDEN);
  // slot for (g,s,block): flagsBase + ((g*2+s)*GB + block)*16   (64B apart)

  // ---- weights -> LDS (skewed layout), once ----
  for (int r = 0; r < ROWS; ++r) {
    const float* W = (r < 4) ? Wf : (r < 8) ? Wi : (r < 12) ? Wo : Wc;
    const float* src = W + (size_t)(u0 + (r & 3)) * GD;
    const int skw = (r >> 2) * 4;
    float* dh = sWh + r * SWHS + skw;
    float* dx = sWx + r * SWXS + skw;
    for (int col = tid; col < GD; col += NTHR) {
      float v = src[col];
      if (col < HIDDEN) dh[col] = v;
      else              dx[col - HIDDEN] = v;
    }
  }
  if (tid < ROWS) {
    const float* bv = (tid < 4) ? bf : (tid < 8) ? bi : (tid < 12) ? bo : bc;
    sB[tid] = bv[u0 + (tid & 3)];
  }
  if (tid < SUBS * UPB * CPG) {              // 128
    ((float*)sC)[tid] = 0.0f;
    ((float*)sM)[tid] = -3.402823e38f;
  }

  // GEMM tiling: 512 thr = 4 cg x 4 rg x 32 ks; frag 4 rows x 4 chains;
  // k-slice = 16 h-k + 8 x-k per thread (768 total).
  const int cg = tid & 3;
  const int rg = (tid >> 2) & 3;
  const int ks = tid >> 4;

  const int stg_c = tid >> 5;      // staging chain 0..15
  const int stg_s = tid & 31;      // staging lane

  const float* pH0  = sH  + (cg * 4) * SHS  + cg * 4;
  const float* pX0  = sX  + (cg * 4) * SXS  + cg * 4;
  const float* pW0  = sWh + (rg * 4) * SWHS + rg * 4;
  const float* pWx0 = sWx + (rg * 4) * SWXS + rg * 4;

  // prefetch x_0 for both sub-batches
  float4 rx0[SUBS], rx1[SUBS];
  #pragma unroll
  for (int s = 0; s < SUBS; ++s) {
    const int chain = g * 32 + s * CPG + stg_c;
    int id0 = ids[(size_t)chain * SEQ];
    const float4* xs = (const float4*)(emb + (size_t)id0 * EMBED);
    rx0[s] = xs[stg_s * 2];
    rx1[s] = xs[stg_s * 2 + 1];
  }
  __syncthreads();

  for (int t = 0; t < SEQ; ++t) {
    const int pb = t & 1;
    const unsigned tu = (unsigned)t;

    #pragma unroll
    for (int s = 0; s < SUBS; ++s) {
      const int chBase = g * 32 + s * CPG;
      unsigned* myFlags = flagsBase + (size_t)(g * 2 + s) * GB * 16;

      // ---- poll: all 128 producers of this sub-batch published h_t.
      // Expected to pass on the first check: flags were set one full
      // sub-step (~2us) ago, hidden behind the other sub-batch's work.
      if (tid < 64) {
        const unsigned* f0 = myFlags + tid * 16;
        const unsigned* f1 = myFlags + (tid + 64) * 16;
        for (;;) {
          unsigned v0 = __hip_atomic_load(f0, __ATOMIC_RELAXED,
                                          __HIP_MEMORY_SCOPE_AGENT);
          unsigned v1 = __hip_atomic_load(f1, __ATOMIC_RELAXED,
                                          __HIP_MEMORY_SCOPE_AGENT);
          if (__all((v0 >= tu) && (v1 >= tu))) break;
          __builtin_amdgcn_s_sleep(1);
        }
      }
      __atomic_signal_fence(__ATOMIC_ACQUIRE);
      __syncthreads();

      // ---- stage h_t (coherent loads), write x_t, prefetch x_{t+1} ----
      {
        const float* hs = hbuf + ((size_t)pb * BATCH + chBase + stg_c) * HIDDEN;
        float* dh = sH + stg_c * SHS + (stg_c >> 2) * 4;
        #pragma unroll
        for (int kk = 0; kk < 16; ++kk) {
          float v = __hip_atomic_load(hs + stg_s + kk * 32, __ATOMIC_RELAXED,
                                      __HIP_MEMORY_SCOPE_AGENT);
          dh[stg_s + kk * 32] = v;
        }
        float* dx = sX + stg_c * SXS + (stg_c >> 2) * 4 + stg_s * 8;
        *(float4*)dx = rx0[s];
        *(float4*)(dx + 4) = rx1[s];
        const int tn = (t + 1 < SEQ) ? t + 1 : SEQ - 1;
        int idn = ids[(size_t)(chBase + stg_c) * SEQ + tn];
        const float4* xs = (const float4*)(emb + (size_t)idn * EMBED);
        rx0[s] = xs[stg_s * 2];
        rx1[s] = xs[stg_s * 2 + 1];
      }
      __syncthreads();

      // ---- GEMM: acc[4 rows][4 chains] over this thread's k-slice ----
      float acc[4][4];
      #pragma unroll
      for (int a = 0; a < 4; ++a)
        #pragma unroll
        for (int b2 = 0; b2 < 4; ++b2) acc[a][b2] = 0.0f;
      {
        const float* px  = pX0 + ks * 8;
        const float* pwx = pWx0 + ks * 8;
        #pragma unroll
        for (int kk = 0; kk < 2; ++kk) {
          float4 xv[4], wv[4];
          #pragma unroll
          for (int ci = 0; ci < 4; ++ci)
            xv[ci] = *(const float4*)(px + ci * SXS + kk * 4);
          #pragma unroll
          for (int ri = 0; ri < 4; ++ri)
            wv[ri] = *(const float4*)(pwx + ri * SWXS + kk * 4);
          #pragma unroll
          for (int ri = 0; ri < 4; ++ri)
            #pragma unroll
            for (int ci = 0; ci < 4; ++ci) {
              acc[ri][ci] = fmaf(wv[ri].x, xv[ci].x, acc[ri][ci]);
              acc[ri][ci] = fmaf(wv[ri].y, xv[ci].y, acc[ri][ci]);
              acc[ri][ci] = fmaf(wv[ri].z, xv[ci].z, acc[ri][ci]);
              acc[ri][ci] = fmaf(wv[ri].w, xv[ci].w, acc[ri][ci]);
            }
        }
        const float* ph = pH0 + ks * 16;
        const float* pw = pW0 + ks * 16;
        #pragma unroll
        for (int kk = 0; kk < 4; ++kk) {
          float4 hv[4], wv[4];
          #pragma unroll
          for (int ci = 0; ci < 4; ++ci)
            hv[ci] = *(const float4*)(ph + ci * SHS + kk * 4);
          #pragma unroll
          for (int ri = 0; ri < 4; ++ri)
            wv[ri] = *(const float4*)(pw + ri * SWHS + kk * 4);
          #pragma unroll
          for (int ri = 0; ri < 4; ++ri)
            #pragma unroll
            for (int ci = 0; ci < 4; ++ci) {
              acc[ri][ci] = fmaf(wv[ri].x, hv[ci].x, acc[ri][ci]);
              acc[ri][ci] = fmaf(wv[ri].y, hv[ci].y, acc[ri][ci]);
              acc[ri][ci] = fmaf(wv[ri].z, hv[ci].z, acc[ri][ci]);
              acc[ri][ci] = fmaf(wv[ri].w, hv[ci].w, acc[ri][ci]);
            }
        }
      }
      __syncthreads();               // done reading sH; reuse as scratch

      // ---- k-split partials -> scratch (rank == tid; stride 17) ----
      {
        float* red = sH;
        #pragma unroll
        for (int ri = 0; ri < 4; ++ri)
          #pragma unroll
          for (int ci = 0; ci < 4; ++ci)
            red[tid * 17 + ri * 4 + ci] = acc[ri][ci];
      }
      __syncthreads();

      // ---- reduce + activation (256 threads, 1 gate value each) ----
      if (tid < 256) {
        const int row = tid >> 4, ch = tid & 15;
        const int base = (row >> 2) * 4 + (ch >> 2);
        const int sub  = (row & 3) * 4 + (ch & 3);
        float a = sB[row];
        #pragma unroll
        for (int q = 0; q < 32; ++q)
          a += sH[(q * 16 + base) * 17 + sub];
        sG[row][ch] = (row < 12) ? 1.0f / (1.0f + expf(-a)) : tanhf(a);
      }
      __syncthreads();

      // ---- combine + state + coherent h publish (64 threads) ----
      if (tid < 64) {
        const int uu = tid >> 4, ch = tid & 15;
        float f  = sG[uu][ch];
        float i_ = sG[4 + uu][ch];
        float o  = sG[8 + uu][ch];
        float gg = sG[12 + uu][ch];
        float cn = f * sC[s][uu][ch] + i_ * gg;
        float h  = o * tanhf(cn);
        sC[s][uu][ch] = cn;
        sM[s][uu][ch] = fmaxf(sM[s][uu][ch], h);
        __hip_atomic_store(
            hbuf + ((size_t)(pb ^ 1) * BATCH + chBase + ch) * HIDDEN + u0 + uu,
            h, __ATOMIC_RELAXED, __HIP_MEMORY_SCOPE_AGENT);
      }
      __syncthreads();               // drains vmcnt -> h stores LLC-visible

      if (tid == 0)
        __hip_atomic_store(myFlags + j * 16, (unsigned)(t + 1),
                           __ATOMIC_RELAXED, __HIP_MEMORY_SCOPE_AGENT);
    }
  }

  // ---- publish running max for both sub-batches, final flags ----
  if (tid < SUBS * UPB * CPG) {      // 128
    const int s = tid >> 6, uu = (tid >> 4) & 3, ch = tid & 15;
    __hip_atomic_store(
        wmax + (size_t)(g * 32 + s * CPG + ch) * HIDDEN + u0 + uu,
        sM[s][uu][ch], __ATOMIC_RELAXED, __HIP_MEMORY_SCOPE_AGENT);
  }
  __syncthreads();
  if (tid == 0) {
    __hip_atomic_store(flagsBase + ((size_t)(g * 2 + 0) * GB + j) * 16,
                       (unsigned)(SEQ + 1), __ATOMIC_RELAXED,
                       __HIP_MEMORY_SCOPE_AGENT);
    __hip_atomic_store(flagsBase + ((size_t)(g * 2 + 1) * GB + j) * 16,
                       (unsigned)(SEQ + 1), __ATOMIC_RELAXED,
                       __HIP_MEMORY_SCOPE_AGENT);
  }

  // ---- head GEMV on the two group-leader blocks (32 chains each) ----
  if (j == 0) {
    const unsigned done = (unsigned)(SEQ + 1);
    if (tid < 64) {
      const unsigned* fA = flagsBase + ((size_t)(g * 2 + 0) * GB) * 16;
      const unsigned* fB = flagsBase + ((size_t)(g * 2 + 1) * GB) * 16;
      for (;;) {
        unsigned a0 = __hip_atomic_load(fA + tid * 16, __ATOMIC_RELAXED,
                                        __HIP_MEMORY_SCOPE_AGENT);
        unsigned a1 = __hip_atomic_load(fA + (tid + 64) * 16, __ATOMIC_RELAXED,
                                        __HIP_MEMORY_SCOPE_AGENT);
        unsigned b0 = __hip_atomic_load(fB + tid * 16, __ATOMIC_RELAXED,
                                        __HIP_MEMORY_SCOPE_AGENT);
        unsigned b1 = __hip_atomic_load(fB + (tid + 64) * 16, __ATOMIC_RELAXED,
                                        __HIP_MEMORY_SCOPE_AGENT);
        if (__all((a0 >= done) && (a1 >= done) && (b0 >= done) && (b1 >= done)))
          break;
        __builtin_amdgcn_s_sleep(1);
      }
    }
    __atomic_signal_fence(__ATOMIC_ACQUIRE);
    __syncthreads();

    const int ch = tid & 31, cls = (tid >> 5) & 3, us = tid >> 7;  // us 0..3
    const float* mrow = wmax + (size_t)(g * 32 + ch) * HIDDEN + us * 128;
    const float* wrow = fcw + (size_t)cls * HIDDEN + us * 128;
    float sAcc = 0.0f;
    for (int q = 0; q < 128; ++q) {
      float v = __hip_atomic_load(mrow + q, __ATOMIC_RELAXED,
                                  __HIP_MEMORY_SCOPE_AGENT);
      sAcc = fmaf(v, wrow[q], sAcc);
    }
    float* red2 = sH;                 // 512 floats scratch, layout == tid
    red2[tid] = sAcc;
    __syncthreads();
    if (tid < 128) {
      const int ch2 = tid & 31, cls2 = tid >> 5;
      float tot = fcb[cls2];
      #pragma unroll
      for (int q = 0; q < 4; ++q) tot += red2[q * 128 + tid];
      out[(g * 32 + ch2) * CLASSES + cls2] = tot;
    }
  }
}

extern "C" void kernel_launch(void* const* d_in, const int* in_sizes, int n_in,
                              void* d_out, int out_size, void* d_ws, size_t ws_size,
                              hipStream_t stream) {
  const int*   ids = (const int*)  d_in[0];
  const float* emb = (const float*)d_in[1];
  const float* Wf  = (const float*)d_in[2];
  const float* bf  = (const float*)d_in[3];
  const float* Wi  = (const float*)d_in[4];
  const float* bi  = (const float*)d_in[5];
  const float* Wo  = (const float*)d_in[6];
  const float* bo  = (const float*)d_in[7];
  const float* Wc  = (const float*)d_in[8];
  const float* bc  = (const float*)d_in[9];
  const float* fcw = (const float*)d_in[10];
  const float* fcb = (const float*)d_in[11];

  // zero h0 (hbuf buffer 0) and the flag area
  hipMemsetAsync(d_ws, 0, (size_t)BATCH * HIDDEN * sizeof(float), stream);
  hipMemsetAsync((char*)d_ws + (size_t)3 * BATCH * HIDDEN * sizeof(float),
                 0, (size_t)GROUPS * SUBS * GB * 16 * sizeof(unsigned), stream);

  lstm_persistent<<<dim3(NBLK), dim3(NTHR), 0, stream>>>(
      ids, emb, Wf, bf, Wi, bi, Wo, bo, Wc, bc, fcw, fcb,
      (float*)d_out, (float*)d_ws);
}